// Round 8
// baseline (828.777 us; speedup 1.0000x reference)
//
#include <hip/hip_runtime.h>

#define NNODES 100000
#define NEDGES 500000
#define DD 128
#define NG 6250        // 16-row groups (100000/16 exact)
#define NBUK_L 782     // buckets per list: ceil(100000/128)
#define NBUK 1564      // total buckets (2 lists)
#define BCAP 896       // bucket capacity: mean 640, sigma 25 -> +10 sigma
#define BINB 123       // bin blocks (123 * 8192 >= 1M edges)
#define ZENT ((unsigned int)NNODES << 7)  // padding entry -> zero row, node 0

typedef __attribute__((ext_vector_type(8))) short short8v;
typedef __attribute__((ext_vector_type(4))) float f32x4;

__device__ __forceinline__ unsigned short f2bf(float f) {
    unsigned int u = __float_as_uint(f);
    return (unsigned short)((u + 0x7FFFu + ((u >> 16) & 1u)) >> 16);
}
__device__ __forceinline__ unsigned int f2bf2(float a, float b) {
    return (unsigned int)f2bf(a) | ((unsigned int)f2bf(b) << 16);
}
__device__ __forceinline__ float bflo(unsigned int v) {
    return __uint_as_float(v << 16);
}
__device__ __forceinline__ float bfhi(unsigned int v) {
    return __uint_as_float(v & 0xFFFF0000u);
}

// ---------------------------------------------------------------------------
// Init: blocks [0,7) zero the 1564 bucket cursors; block 7 detects int64 vs
// int32 edge storage (odd 32-bit words all zero => int64).
// ---------------------------------------------------------------------------
__global__ __launch_bounds__(256) void init_kernel(
        int* __restrict__ gcur, const unsigned int* __restrict__ e,
        int* __restrict__ flag) {
    if (blockIdx.x < 7) {
        const int i = blockIdx.x * 256 + threadIdx.x;
        if (i < NBUK) gcur[i] = 0;
        return;
    }
    __shared__ unsigned int s_acc;
    if (threadIdx.x == 0) s_acc = 0u;
    __syncthreads();
    unsigned int v = 0u;
    for (int i = threadIdx.x; i < 4096; i += 256)
        v |= e[2 * i + 1];
    for (int off = 32; off > 0; off >>= 1)
        v |= __shfl_down(v, off, 64);
    if ((threadIdx.x & 63) == 0) atomicOr(&s_acc, v);
    __syncthreads();
    if (threadIdx.x == 0) *flag = (s_acc == 0u) ? 1 : 0;
}

// ---------------------------------------------------------------------------
// Fused prep. Block roles:
//   [0,BINB):      edge binning — 8192 edges/block. LDS histogram over 1564
//                  buckets, ONE global atomic per (block,bucket) to reserve,
//                  then place entries (src<<7 | dst&127) at LDS-cursor
//                  positions. Per-block bucket runs (~5 entries) share cache
//                  lines -> ~300K line ops total vs 2M in the per-edge scheme.
//   [BINB,+24):    W (fp32 [384][128]) -> fragment-packed bf16 wb.
//   BINB+24:       zero row of xb at index NNODES (padding target).
//   [BINB+25,+512): x (fp32) -> xb (bf16 row-major).
// ---------------------------------------------------------------------------
__global__ __launch_bounds__(256) void prep_kernel(
        const float4* __restrict__ x4, uint2* __restrict__ xb2,
        const float* __restrict__ W, unsigned short* __restrict__ wb,
        const void* __restrict__ pe, const void* __restrict__ ne,
        const int* __restrict__ flag,
        int* __restrict__ gcur, unsigned int* __restrict__ regions) {
    const int b = blockIdx.x;
    if (b < BINB) {
        __shared__ int hist[NBUK];
        __shared__ int gbase[NBUK];
        const int tid = threadIdx.x;
        for (int i = tid; i < NBUK; i += 256) hist[i] = 0;
        __syncthreads();
        const int e0 = b * 8192;
        const int fl = *flag;
        // pass 1: LDS histogram (dst only)
        for (int k = 0; k < 32; ++k) {
            const int i = e0 + k * 256 + tid;
            if (i < 2 * NEDGES) {
                const int list = i >= NEDGES;
                const int e = i - list * NEDGES;
                const void* ed = list ? ne : pe;
                int d;
                if (fl) d = (int)((const long long*)ed)[NEDGES + e];
                else    d = ((const int*)ed)[NEDGES + e];
                atomicAdd(&hist[list * NBUK_L + (d >> 7)], 1);
            }
        }
        __syncthreads();
        // reserve: one global atomic per non-empty bucket
        for (int i = tid; i < NBUK; i += 256) {
            const int h = hist[i];
            gbase[i] = h ? atomicAdd(&gcur[i], h) : 0;
            hist[i] = 0;  // reuse as local cursor
        }
        __syncthreads();
        // pass 2: place entries
        for (int k = 0; k < 32; ++k) {
            const int i = e0 + k * 256 + tid;
            if (i < 2 * NEDGES) {
                const int list = i >= NEDGES;
                const int e = i - list * NEDGES;
                int s, d;
                if (fl) {
                    const long long* p = (const long long*)(list ? ne : pe);
                    s = (int)p[e]; d = (int)p[NEDGES + e];
                } else {
                    const int* p = (const int*)(list ? ne : pe);
                    s = p[e]; d = p[NEDGES + e];
                }
                const int bk = list * NBUK_L + (d >> 7);
                const int pos = gbase[bk] + atomicAdd(&hist[bk], 1);
                if (pos < BCAP)
                    regions[(size_t)bk * BCAP + pos] =
                        ((unsigned int)s << 7) | (unsigned int)(d & 127);
            }
        }
    } else if (b < BINB + 24) {
        // frag (s,nf) at ((s*8+nf)*64+lane)*8 shorts; lane l holds
        // B[k=32s+(l>>4)*8+j][n=16nf+(l&15)], j=0..7.
        const int t = (b - BINB) * 256 + threadIdx.x;
        const int l = t & 63;
        const int nf = (t >> 6) & 7;
        const int s = t >> 9;
        const int n = nf * 16 + (l & 15);
        const int k0 = s * 32 + (l >> 4) * 8;
        unsigned short* o = wb + (size_t)t * 8;
#pragma unroll
        for (int j = 0; j < 8; ++j)
            o[j] = f2bf(W[(size_t)(k0 + j) * DD + n]);
    } else if (b == BINB + 24) {
        if (threadIdx.x < 64)
            ((unsigned int*)xb2)[(size_t)NNODES * 64 + threadIdx.x] = 0u;
    } else {
        const int n = NNODES * DD / 4;
        for (int i = (b - BINB - 25) * 256 + threadIdx.x; i < n; i += 512 * 256) {
            const float4 v = x4[i];
            uint2 o;
            o.x = f2bf2(v.x, v.y);
            o.y = f2bf2(v.z, v.w);
            xb2[i] = o;
        }
    }
}

// ---------------------------------------------------------------------------
// Aggregate: one block per bucket (128 nodes). 64 KB LDS fp32 tile; waves
// stream the bucket's contiguous edge list 8-deep (row loads batched for
// MLP), LDS atomicAdd (ds_add_f32, 2-way bank-free), then coalesced bf16
// writeout interleaved into out: row r words [128r,128r+64)=pos,
// [128r+64,128r+128)=neg. Padding entries read the zero row -> add 0.
// ---------------------------------------------------------------------------
__global__ __launch_bounds__(256) void agg_kernel(
        const unsigned int* __restrict__ xbw,
        const int* __restrict__ gcur, const unsigned int* __restrict__ regions,
        unsigned int* __restrict__ outb) {
    __shared__ float agg[128 * 128];  // 64 KB
    const int b = blockIdx.x;
    const int list = b >= NBUK_L;
    const int node0 = (b - list * NBUK_L) * 128;
    const int tid = threadIdx.x;
    const int wid = tid >> 6;
    const int lane = tid & 63;

#pragma unroll
    for (int i = 0; i < 16; ++i)
        ((float4*)agg)[tid + i * 256] = make_float4(0.f, 0.f, 0.f, 0.f);
    __syncthreads();

    int n = gcur[b];
    n = n < BCAP ? n : BCAP;
    const unsigned int* __restrict__ reg = regions + (size_t)b * BCAP;

    for (int base = wid * 8; base < n; base += 32) {
        unsigned int ent[8];
#pragma unroll
        for (int j = 0; j < 8; ++j) {
            const int i = base + j;
            ent[j] = (i < n) ? reg[i] : ZENT;
        }
        unsigned int v[8];
#pragma unroll
        for (int j = 0; j < 8; ++j)
            v[j] = xbw[(size_t)(ent[j] >> 7) * 64 + lane];
#pragma unroll
        for (int j = 0; j < 8; ++j) {
            float* a = agg + (ent[j] & 127u) * 128 + lane * 2;
            atomicAdd(a, bflo(v[j]));
            atomicAdd(a + 1, bfhi(v[j]));
        }
    }
    __syncthreads();

    for (int k = 0; k < 32; ++k) {
        const int nl = wid * 32 + k;
        const int node = node0 + nl;
        if (node < NNODES)
            outb[(size_t)node * 128 + list * 64 + lane] =
                f2bf2(agg[nl * 128 + lane * 2], agg[nl * 128 + lane * 2 + 1]);
    }
}

// ---------------------------------------------------------------------------
// MFMA GEMM: out = [xb | aggp | aggn] @ W + b (all bf16 inputs, fp32 out).
// 256 thr = 4 waves; wave w covers groups {8*blk + 2w, +1} (16 rows each),
// full 128-col width as 8 n-frags. No LDS, no __syncthreads.
// Alias note: agg lives interleaved inside `out`; each wave stores only its
// own rows and only after all its own A reads -> no cross-wave hazard.
// ---------------------------------------------------------------------------
__global__ __launch_bounds__(256) void gemm_kernel(
        const unsigned short* __restrict__ xb,
        const unsigned short* __restrict__ aggb,  // == out bytes as bf16
        const unsigned short* __restrict__ wb,
        const float* __restrict__ bias,
        float* __restrict__ out) {
    const int lane = threadIdx.x & 63;
    const int wid = threadIdx.x >> 6;
    const int g0 = blockIdx.x * 8 + wid * 2;
    const int lm = lane & 15;
    const int lk = lane >> 4;

    f32x4 acc[2][8];
#pragma unroll
    for (int gi = 0; gi < 2; ++gi)
#pragma unroll
        for (int nf = 0; nf < 8; ++nf)
            acc[gi][nf] = (f32x4)(0.f);

    for (int c = 0; c < 3; ++c) {
#pragma unroll
        for (int s = 0; s < 4; ++s) {
            short8v a[2];
#pragma unroll
            for (int gi = 0; gi < 2; ++gi) {
                const int g = g0 + gi;
                if (g < NG) {
                    const size_t row = (size_t)g * 16 + lm;
                    const unsigned short* ap =
                        (c == 0) ? xb + row * 128 + s * 32 + lk * 8
                                 : aggb + row * 256 + (c - 1) * 128 + s * 32 + lk * 8;
                    a[gi] = *(const short8v*)ap;
                } else {
                    a[gi] = (short8v)0;
                }
            }
            const short8v* __restrict__ bp =
                (const short8v*)wb + ((size_t)(c * 4 + s) * 8) * 64 + lane;
#pragma unroll
            for (int nf = 0; nf < 8; ++nf) {
                const short8v b = bp[nf * 64];
                acc[0][nf] = __builtin_amdgcn_mfma_f32_16x16x32_bf16(
                    a[0], b, acc[0][nf], 0, 0, 0);
                acc[1][nf] = __builtin_amdgcn_mfma_f32_16x16x32_bf16(
                    a[1], b, acc[1][nf], 0, 0, 0);
            }
        }
    }

#pragma unroll
    for (int gi = 0; gi < 2; ++gi) {
        const int g = g0 + gi;
        if (g >= NG) break;
        const int rbase = g * 16 + lk * 4;
#pragma unroll
        for (int nf = 0; nf < 8; ++nf) {
            const int col = nf * 16 + lm;
            const float bv = bias[col];
#pragma unroll
            for (int r = 0; r < 4; ++r)
                out[(size_t)(rbase + r) * 128 + col] = acc[gi][nf][r] + bv;
        }
    }
}

extern "C" void kernel_launch(void* const* d_in, const int* in_sizes, int n_in,
                              void* d_out, int out_size, void* d_ws, size_t ws_size,
                              hipStream_t stream) {
    const float* x     = (const float*)d_in[0];
    const void*  pos_e = d_in[1];
    const void*  neg_e = d_in[2];
    const float* W     = (const float*)d_in[3];
    const float* bias  = (const float*)d_in[4];
    float*       out   = (float*)d_out;

    const size_t XB = ((size_t)NNODES + 1) * DD * 2;   // 25.6 MB + zero row
    const size_t WB = 12 * 8 * 64 * 8 * 2;             // 98304 B
    const size_t GB = 8192;                            // cursors (NBUK ints)
    const size_t RB = (size_t)NBUK * BCAP * 4;         // 5.6 MB regions

    char* ws = (char*)d_ws;
    int* flag = (int*)ws;
    size_t off = 256;
    unsigned int*   xb      = (unsigned int*)(ws + off);   off += XB;
    unsigned short* wb      = (unsigned short*)(ws + off); off += WB;
    int*            gcur    = (int*)(ws + off);            off += GB;
    unsigned int*   regions = (unsigned int*)(ws + off);   off += RB;
    (void)ws_size;

    init_kernel<<<8, 256, 0, stream>>>(gcur, (const unsigned int*)pos_e, flag);

    prep_kernel<<<BINB + 25 + 512, 256, 0, stream>>>(
        (const float4*)x, (uint2*)xb, W, wb, pos_e, neg_e, flag, gcur, regions);

    agg_kernel<<<NBUK, 256, 0, stream>>>(xb, gcur, regions, (unsigned int*)out);

    gemm_kernel<<<(NG + 7) / 8, 256, 0, stream>>>(
        (const unsigned short*)xb, (const unsigned short*)out, wb, bias, out);
}

// Round 9
// 136.146 us; speedup vs baseline: 6.0874x; 6.0874x over previous
//
#include <hip/hip_runtime.h>

#define NNODES 100000
#define NEDGES 500000
#define DD 128
#define NG 6250        // 16-row groups (100000/16 exact)
#define NBUK_L 782     // buckets per list: ceil(100000/128)
#define NBUK 1564      // total buckets (2 lists)
#define BCAP 896       // bucket capacity: mean 640, sigma 25 -> +10 sigma
#define BINB 123       // bin blocks (123 * 8192 >= 1M edges)
#define ZBYTE ((unsigned int)NNODES << 8)  // byte offset of zero row in xb

typedef __attribute__((ext_vector_type(8))) short short8v;
typedef __attribute__((ext_vector_type(4))) float f32x4;

__device__ __forceinline__ unsigned short f2bf(float f) {
    unsigned int u = __float_as_uint(f);
    return (unsigned short)((u + 0x7FFFu + ((u >> 16) & 1u)) >> 16);
}
__device__ __forceinline__ unsigned int f2bf2(float a, float b) {
    return (unsigned int)f2bf(a) | ((unsigned int)f2bf(b) << 16);
}
__device__ __forceinline__ float bflo(unsigned int v) {
    return __uint_as_float(v << 16);
}
__device__ __forceinline__ float bfhi(unsigned int v) {
    return __uint_as_float(v & 0xFFFF0000u);
}

// ---------------------------------------------------------------------------
// Init: blocks [0,7) zero the 1564 bucket cursors; block 7 detects int64 vs
// int32 edge storage (odd 32-bit words all zero => int64).
// ---------------------------------------------------------------------------
__global__ __launch_bounds__(256) void init_kernel(
        int* __restrict__ gcur, const unsigned int* __restrict__ e,
        int* __restrict__ flag) {
    if (blockIdx.x < 7) {
        const int i = blockIdx.x * 256 + threadIdx.x;
        if (i < NBUK) gcur[i] = 0;
        return;
    }
    __shared__ unsigned int s_acc;
    if (threadIdx.x == 0) s_acc = 0u;
    __syncthreads();
    unsigned int v = 0u;
    for (int i = threadIdx.x; i < 4096; i += 256)
        v |= e[2 * i + 1];
    for (int off = 32; off > 0; off >>= 1)
        v |= __shfl_down(v, off, 64);
    if ((threadIdx.x & 63) == 0) atomicOr(&s_acc, v);
    __syncthreads();
    if (threadIdx.x == 0) *flag = (s_acc == 0u) ? 1 : 0;
}

// ---------------------------------------------------------------------------
// Fused prep. Block roles:
//   [0,BINB):      edge binning — 8192 edges/block. LDS int histogram over
//                  1564 buckets, ONE global atomic per (block,bucket), then
//                  place entries (src<<7 | dst&127) at LDS-cursor positions.
//   [BINB,+24):    W (fp32 [384][128]) -> fragment-packed bf16 wb.
//   BINB+24:       zero row of xb at index NNODES (padding target).
//   [BINB+25,+512): x (fp32) -> xb (bf16 row-major).
// ---------------------------------------------------------------------------
__global__ __launch_bounds__(256) void prep_kernel(
        const float4* __restrict__ x4, uint2* __restrict__ xb2,
        const float* __restrict__ W, unsigned short* __restrict__ wb,
        const void* __restrict__ pe, const void* __restrict__ ne,
        const int* __restrict__ flag,
        int* __restrict__ gcur, unsigned int* __restrict__ regions) {
    const int b = blockIdx.x;
    if (b < BINB) {
        __shared__ int hist[NBUK];
        __shared__ int gbase[NBUK];
        const int tid = threadIdx.x;
        for (int i = tid; i < NBUK; i += 256) hist[i] = 0;
        __syncthreads();
        const int e0 = b * 8192;
        const int fl = *flag;
        // pass 1: LDS histogram (dst only), native ds_add_u32
        for (int k = 0; k < 32; ++k) {
            const int i = e0 + k * 256 + tid;
            if (i < 2 * NEDGES) {
                const int list = i >= NEDGES;
                const int e = i - list * NEDGES;
                const void* ed = list ? ne : pe;
                int d;
                if (fl) d = (int)((const long long*)ed)[NEDGES + e];
                else    d = ((const int*)ed)[NEDGES + e];
                atomicAdd(&hist[list * NBUK_L + (d >> 7)], 1);
            }
        }
        __syncthreads();
        // reserve: one global atomic per non-empty bucket
        for (int i = tid; i < NBUK; i += 256) {
            const int h = hist[i];
            gbase[i] = h ? atomicAdd(&gcur[i], h) : 0;
            hist[i] = 0;  // reuse as local cursor
        }
        __syncthreads();
        // pass 2: place entries
        for (int k = 0; k < 32; ++k) {
            const int i = e0 + k * 256 + tid;
            if (i < 2 * NEDGES) {
                const int list = i >= NEDGES;
                const int e = i - list * NEDGES;
                int s, d;
                if (fl) {
                    const long long* p = (const long long*)(list ? ne : pe);
                    s = (int)p[e]; d = (int)p[NEDGES + e];
                } else {
                    const int* p = (const int*)(list ? ne : pe);
                    s = p[e]; d = p[NEDGES + e];
                }
                const int bk = list * NBUK_L + (d >> 7);
                const int pos = gbase[bk] + atomicAdd(&hist[bk], 1);
                if (pos < BCAP)
                    regions[(size_t)bk * BCAP + pos] =
                        ((unsigned int)s << 7) | (unsigned int)(d & 127);
            }
        }
    } else if (b < BINB + 24) {
        // frag (s,nf) at ((s*8+nf)*64+lane)*8 shorts; lane l holds
        // B[k=32s+(l>>4)*8+j][n=16nf+(l&15)], j=0..7.
        const int t = (b - BINB) * 256 + threadIdx.x;
        const int l = t & 63;
        const int nf = (t >> 6) & 7;
        const int s = t >> 9;
        const int n = nf * 16 + (l & 15);
        const int k0 = s * 32 + (l >> 4) * 8;
        unsigned short* o = wb + (size_t)t * 8;
#pragma unroll
        for (int j = 0; j < 8; ++j)
            o[j] = f2bf(W[(size_t)(k0 + j) * DD + n]);
    } else if (b == BINB + 24) {
        if (threadIdx.x < 64)
            ((unsigned int*)xb2)[(size_t)NNODES * 64 + threadIdx.x] = 0u;
    } else {
        const int n = NNODES * DD / 4;
        for (int i = (b - BINB - 25) * 256 + threadIdx.x; i < n; i += 512 * 256) {
            const float4 v = x4[i];
            uint2 o;
            o.x = f2bf2(v.x, v.y);
            o.y = f2bf2(v.z, v.w);
            xb2[i] = o;
        }
    }
}

// ---------------------------------------------------------------------------
// Aggregate: one block per bucket (128 nodes, 256 thr, ~5 KB LDS).
//   1) LDS int histogram of local dst over the bucket's entries
//   2) 128-wide LDS exclusive scan -> segment starts
//   3) place entries sorted by dst as pre-scaled byte offsets (src*256)
//   4) each wave: 32 nodes, register fp32 accumulation with 8-deep batched
//      row loads (padding -> zero row), coalesced bf16 writeout interleaved:
//      row r words [128r,128r+64)=pos, [128r+64,128r+128)=neg.
// No fp atomics anywhere; only native LDS u32 atomics.
// ---------------------------------------------------------------------------
__global__ __launch_bounds__(256) void agg_kernel(
        const char* __restrict__ xbb,
        const int* __restrict__ gcur, const unsigned int* __restrict__ regions,
        unsigned int* __restrict__ outb) {
    __shared__ int cnt[128];
    __shared__ int tmp[128];
    __shared__ int sstart[129];
    __shared__ int scur[128];
    __shared__ unsigned int sorted[BCAP];

    const int b = blockIdx.x;
    const int list = b >= NBUK_L;
    const int node0 = (b - list * NBUK_L) * 128;
    const int tid = threadIdx.x;
    const int wid = tid >> 6;
    const int lane = tid & 63;

    int n = gcur[b];
    n = n < BCAP ? n : BCAP;
    const unsigned int* __restrict__ reg = regions + (size_t)b * BCAP;

    if (tid < 128) cnt[tid] = 0;
    __syncthreads();
    for (int i = tid; i < n; i += 256)
        atomicAdd(&cnt[reg[i] & 127u], 1);
    __syncthreads();
    if (tid < 128) tmp[tid] = cnt[tid];
    __syncthreads();
#pragma unroll
    for (int off = 1; off < 128; off <<= 1) {
        int v = 0;
        if (tid < 128 && tid >= off) v = tmp[tid - off];
        __syncthreads();
        if (tid < 128) tmp[tid] += v;
        __syncthreads();
    }
    if (tid < 128) {
        const int st = tmp[tid] - cnt[tid];
        sstart[tid] = st;
        scur[tid] = st;
    }
    if (tid == 127) sstart[128] = tmp[127];
    __syncthreads();
    for (int i = tid; i < n; i += 256) {
        const unsigned int ent = reg[i];
        const int pos = atomicAdd(&scur[ent & 127u], 1);
        sorted[pos] = (ent & ~127u) << 1;  // src*256 byte offset
    }
    __syncthreads();

    const unsigned int lane4 = lane * 4;
#pragma unroll 1
    for (int k = 0; k < 32; ++k) {
        const int nl = wid * 32 + k;
        const int s0 = sstart[nl], s1 = sstart[nl + 1];
        float ax = 0.f, ay = 0.f;
        for (int base = s0; base < s1; base += 8) {
            unsigned int off[8];
#pragma unroll
            for (int j = 0; j < 8; ++j) {
                const int ii = base + j;
                off[j] = (ii < s1) ? sorted[ii] : ZBYTE;
            }
            unsigned int v[8];
#pragma unroll
            for (int j = 0; j < 8; ++j)
                v[j] = *(const unsigned int*)(xbb + (size_t)(off[j] + lane4));
#pragma unroll
            for (int j = 0; j < 8; ++j) {
                ax += bflo(v[j]);
                ay += bfhi(v[j]);
            }
        }
        const int node = node0 + nl;
        if (node < NNODES)
            outb[(size_t)node * 128 + list * 64 + lane] = f2bf2(ax, ay);
    }
}

// ---------------------------------------------------------------------------
// MFMA GEMM: out = [xb | aggp | aggn] @ W + b (all bf16 inputs, fp32 out).
// 256 thr = 4 waves; wave w covers groups {8*blk + 2w, +1} (16 rows each),
// full 128-col width as 8 n-frags. No LDS, no __syncthreads.
// Alias note: agg lives interleaved inside `out`; each wave stores only its
// own rows and only after all its own A reads -> no cross-wave hazard.
// ---------------------------------------------------------------------------
__global__ __launch_bounds__(256) void gemm_kernel(
        const unsigned short* __restrict__ xb,
        const unsigned short* __restrict__ aggb,  // == out bytes as bf16
        const unsigned short* __restrict__ wb,
        const float* __restrict__ bias,
        float* __restrict__ out) {
    const int lane = threadIdx.x & 63;
    const int wid = threadIdx.x >> 6;
    const int g0 = blockIdx.x * 8 + wid * 2;
    const int lm = lane & 15;
    const int lk = lane >> 4;

    f32x4 acc[2][8];
#pragma unroll
    for (int gi = 0; gi < 2; ++gi)
#pragma unroll
        for (int nf = 0; nf < 8; ++nf)
            acc[gi][nf] = (f32x4)(0.f);

    for (int c = 0; c < 3; ++c) {
#pragma unroll
        for (int s = 0; s < 4; ++s) {
            short8v a[2];
#pragma unroll
            for (int gi = 0; gi < 2; ++gi) {
                const int g = g0 + gi;
                if (g < NG) {
                    const size_t row = (size_t)g * 16 + lm;
                    const unsigned short* ap =
                        (c == 0) ? xb + row * 128 + s * 32 + lk * 8
                                 : aggb + row * 256 + (c - 1) * 128 + s * 32 + lk * 8;
                    a[gi] = *(const short8v*)ap;
                } else {
                    a[gi] = (short8v)0;
                }
            }
            const short8v* __restrict__ bp =
                (const short8v*)wb + ((size_t)(c * 4 + s) * 8) * 64 + lane;
#pragma unroll
            for (int nf = 0; nf < 8; ++nf) {
                const short8v b = bp[nf * 64];
                acc[0][nf] = __builtin_amdgcn_mfma_f32_16x16x32_bf16(
                    a[0], b, acc[0][nf], 0, 0, 0);
                acc[1][nf] = __builtin_amdgcn_mfma_f32_16x16x32_bf16(
                    a[1], b, acc[1][nf], 0, 0, 0);
            }
        }
    }

#pragma unroll
    for (int gi = 0; gi < 2; ++gi) {
        const int g = g0 + gi;
        if (g >= NG) break;
        const int rbase = g * 16 + lk * 4;
#pragma unroll
        for (int nf = 0; nf < 8; ++nf) {
            const int col = nf * 16 + lm;
            const float bv = bias[col];
#pragma unroll
            for (int r = 0; r < 4; ++r)
                out[(size_t)(rbase + r) * 128 + col] = acc[gi][nf][r] + bv;
        }
    }
}

extern "C" void kernel_launch(void* const* d_in, const int* in_sizes, int n_in,
                              void* d_out, int out_size, void* d_ws, size_t ws_size,
                              hipStream_t stream) {
    const float* x     = (const float*)d_in[0];
    const void*  pos_e = d_in[1];
    const void*  neg_e = d_in[2];
    const float* W     = (const float*)d_in[3];
    const float* bias  = (const float*)d_in[4];
    float*       out   = (float*)d_out;

    const size_t XB = ((size_t)NNODES + 1) * DD * 2;   // 25.6 MB + zero row
    const size_t WB = 12 * 8 * 64 * 8 * 2;             // 98304 B
    const size_t GB = 8192;                            // cursors (NBUK ints)
    const size_t RB = (size_t)NBUK * BCAP * 4;         // 5.6 MB regions

    char* ws = (char*)d_ws;
    int* flag = (int*)ws;
    size_t off = 256;
    unsigned int*   xb      = (unsigned int*)(ws + off);   off += XB;
    unsigned short* wb      = (unsigned short*)(ws + off); off += WB;
    int*            gcur    = (int*)(ws + off);            off += GB;
    unsigned int*   regions = (unsigned int*)(ws + off);   off += RB;
    (void)ws_size;

    init_kernel<<<8, 256, 0, stream>>>(gcur, (const unsigned int*)pos_e, flag);

    prep_kernel<<<BINB + 25 + 512, 256, 0, stream>>>(
        (const float4*)x, (uint2*)xb, W, wb, pos_e, neg_e, flag, gcur, regions);

    agg_kernel<<<NBUK, 256, 0, stream>>>(
        (const char*)xb, gcur, regions, (unsigned int*)out);

    gemm_kernel<<<(NG + 7) / 8, 256, 0, stream>>>(
        (const unsigned short*)xb, (const unsigned short*)out, wb, bias, out);
}

// Round 10
// 119.384 us; speedup vs baseline: 6.9421x; 1.1404x over previous
//
#include <hip/hip_runtime.h>

#define NNODES 100000
#define NEDGES 500000
#define DD 128
#define NBUK 1563      // 64-node combined buckets: ceil(100000/64)
#define BCAP 896       // mean 640, sigma 25 -> +10 sigma
#define BINB 123       // bin blocks (123 * 8192 >= 1M edges)
#define ZBYTE ((unsigned int)NNODES << 8)  // byte offset of zero row in xb

typedef __attribute__((ext_vector_type(8))) short short8v;
typedef __attribute__((ext_vector_type(4))) float f32x4;

__device__ __forceinline__ unsigned short f2bf(float f) {
    unsigned int u = __float_as_uint(f);
    return (unsigned short)((u + 0x7FFFu + ((u >> 16) & 1u)) >> 16);
}
__device__ __forceinline__ unsigned int f2bf2(float a, float b) {
    return (unsigned int)f2bf(a) | ((unsigned int)f2bf(b) << 16);
}
__device__ __forceinline__ float bflo(unsigned int v) {
    return __uint_as_float(v << 16);
}
__device__ __forceinline__ float bfhi(unsigned int v) {
    return __uint_as_float(v & 0xFFFF0000u);
}

// ---------------------------------------------------------------------------
// Init: blocks [0,7) zero the 1563 bucket cursors; block 7 detects int64 vs
// int32 edge storage (odd 32-bit words all zero => int64).
// ---------------------------------------------------------------------------
__global__ __launch_bounds__(256) void init_kernel(
        int* __restrict__ gcur, const unsigned int* __restrict__ e,
        int* __restrict__ flag) {
    if (blockIdx.x < 7) {
        const int i = blockIdx.x * 256 + threadIdx.x;
        if (i < NBUK) gcur[i] = 0;
        return;
    }
    __shared__ unsigned int s_acc;
    if (threadIdx.x == 0) s_acc = 0u;
    __syncthreads();
    unsigned int v = 0u;
    for (int i = threadIdx.x; i < 4096; i += 256)
        v |= e[2 * i + 1];
    for (int off = 32; off > 0; off >>= 1)
        v |= __shfl_down(v, off, 64);
    if ((threadIdx.x & 63) == 0) atomicOr(&s_acc, v);
    __syncthreads();
    if (threadIdx.x == 0) *flag = (s_acc == 0u) ? 1 : 0;
}

// ---------------------------------------------------------------------------
// Fused prep. Block roles:
//   [0,BINB):      edge binning, 8192 edges/block, BOTH passes batched 8-deep
//                  (8 independent edge loads in flight before the dependent
//                  LDS atomics — kills the ~700cy load->atomic chains).
//   [BINB,+24):    W (fp32 [384][128]) -> fragment-packed bf16 wb.
//   BINB+24:       zero row of xb at index NNODES (padding/clamp target).
//   [BINB+25,+512): x (fp32) -> xb (bf16 row-major).
// ---------------------------------------------------------------------------
__global__ __launch_bounds__(256) void prep_kernel(
        const float4* __restrict__ x4, uint2* __restrict__ xb2,
        const float* __restrict__ W, unsigned short* __restrict__ wb,
        const void* __restrict__ pe, const void* __restrict__ ne,
        const int* __restrict__ flag,
        int* __restrict__ gcur, unsigned int* __restrict__ regions) {
    const int b = blockIdx.x;
    if (b < BINB) {
        __shared__ int hist[NBUK];
        __shared__ int gbase[NBUK];
        const int tid = threadIdx.x;
        for (int i = tid; i < NBUK; i += 256) hist[i] = 0;
        __syncthreads();
        const int e0 = b * 8192;
        const int fl = *flag;
        // pass 1: LDS histogram of bucket ids, 8-deep batched loads
        for (int k0 = 0; k0 < 32; k0 += 8) {
            int dv[8];
            bool ok[8];
#pragma unroll
            for (int j = 0; j < 8; ++j) {
                const int i = e0 + (k0 + j) * 256 + tid;
                ok[j] = i < 2 * NEDGES;
                const int ic = ok[j] ? i : 0;
                const int list = ic >= NEDGES;
                const int e = ic - list * NEDGES;
                const void* ed = list ? ne : pe;
                dv[j] = fl ? (int)((const long long*)ed)[NEDGES + e]
                           : ((const int*)ed)[NEDGES + e];
            }
#pragma unroll
            for (int j = 0; j < 8; ++j)
                if (ok[j]) atomicAdd(&hist[dv[j] >> 6], 1);
        }
        __syncthreads();
        // reserve: one global atomic per (block,bucket)
        for (int i = tid; i < NBUK; i += 256) {
            const int h = hist[i];
            gbase[i] = h ? atomicAdd(&gcur[i], h) : 0;
            hist[i] = 0;  // reuse as local cursor
        }
        __syncthreads();
        // pass 2: place entries, 8-deep batched
        for (int k0 = 0; k0 < 32; k0 += 8) {
            unsigned int ent[8];
            int bk[8];
            bool ok[8];
#pragma unroll
            for (int j = 0; j < 8; ++j) {
                const int i = e0 + (k0 + j) * 256 + tid;
                ok[j] = i < 2 * NEDGES;
                const int ic = ok[j] ? i : 0;
                const int list = ic >= NEDGES;
                const int e = ic - list * NEDGES;
                int s, d;
                if (fl) {
                    const long long* p = (const long long*)(list ? ne : pe);
                    s = (int)p[e]; d = (int)p[NEDGES + e];
                } else {
                    const int* p = (const int*)(list ? ne : pe);
                    s = p[e]; d = p[NEDGES + e];
                }
                bk[j] = d >> 6;
                ent[j] = ((unsigned int)s << 7) |
                         ((unsigned int)(d & 63) << 1) | (unsigned int)list;
            }
            int pos[8];
#pragma unroll
            for (int j = 0; j < 8; ++j)
                if (ok[j]) pos[j] = gbase[bk[j]] + atomicAdd(&hist[bk[j]], 1);
#pragma unroll
            for (int j = 0; j < 8; ++j)
                if (ok[j] && pos[j] < BCAP)
                    regions[(size_t)bk[j] * BCAP + pos[j]] = ent[j];
        }
    } else if (b < BINB + 24) {
        // frag (s,nf) at ((s*8+nf)*64+lane)*8 shorts; lane l holds
        // B[k=32s+(l>>4)*8+j][n=16nf+(l&15)], j=0..7.
        const int t = (b - BINB) * 256 + threadIdx.x;
        const int l = t & 63;
        const int nf = (t >> 6) & 7;
        const int s = t >> 9;
        const int n = nf * 16 + (l & 15);
        const int k0 = s * 32 + (l >> 4) * 8;
        unsigned short* o = wb + (size_t)t * 8;
#pragma unroll
        for (int j = 0; j < 8; ++j)
            o[j] = f2bf(W[(size_t)(k0 + j) * DD + n]);
    } else if (b == BINB + 24) {
        if (threadIdx.x < 64)
            ((unsigned int*)xb2)[(size_t)NNODES * 64 + threadIdx.x] = 0u;
    } else {
        const int n = NNODES * DD / 4;
        for (int i = (b - BINB - 25) * 256 + threadIdx.x; i < n; i += 512 * 256) {
            const float4 v = x4[i];
            uint2 o;
            o.x = f2bf2(v.x, v.y);
            o.y = f2bf2(v.z, v.w);
            xb2[i] = o;
        }
    }
}

// ---------------------------------------------------------------------------
// Fused aggregate + GEMM: one block per 64-node bucket (both lists).
//   1) counting sort of the bucket's entries by (node,list) segment (LDS int
//      atomics + 128-wide scan) -> sorted src byte offsets
//   2) register gather: wave w owns segments [32w,32w+32) = nodes
//      [16w,16w+16) x {pos,neg}; 8-deep batched row loads, zero-row padding
//   3) bf16 agg -> LDS tile [64][264] (528B pitch -> 2-way banks, free)
//   4) MFMA: wave w computes rows node0+16w..+15, 128 cols; A-frags c=0 from
//      xb (global), c=1/2 from the LDS tile; fp32 out + bias, direct store.
// No global agg round-trip; out written exactly once.
// ---------------------------------------------------------------------------
__global__ __launch_bounds__(256) void aggemm_kernel(
        const char* __restrict__ xbb,
        const int* __restrict__ gcur, const unsigned int* __restrict__ regions,
        const unsigned short* __restrict__ wb,
        const float* __restrict__ bias,
        float* __restrict__ out) {
    __shared__ unsigned short tile[64 * 264];  // 33.8 KB
    __shared__ unsigned int sorted[BCAP];
    __shared__ int cnt[128];
    __shared__ int tmp[128];
    __shared__ int sstart[129];
    __shared__ int scur[128];

    const int b = blockIdx.x;
    const int node0 = b * 64;
    const int tid = threadIdx.x;
    const int wid = tid >> 6;
    const int lane = tid & 63;

    int n = gcur[b];
    n = n < BCAP ? n : BCAP;
    const unsigned int* __restrict__ reg = regions + (size_t)b * BCAP;

    if (tid < 128) cnt[tid] = 0;
    __syncthreads();
    for (int i = tid; i < n; i += 256)
        atomicAdd(&cnt[reg[i] & 127u], 1);
    __syncthreads();
    if (tid < 128) tmp[tid] = cnt[tid];
    __syncthreads();
#pragma unroll
    for (int off = 1; off < 128; off <<= 1) {
        int v = 0;
        if (tid < 128 && tid >= off) v = tmp[tid - off];
        __syncthreads();
        if (tid < 128) tmp[tid] += v;
        __syncthreads();
    }
    if (tid < 128) {
        const int st = tmp[tid] - cnt[tid];
        sstart[tid] = st;
        scur[tid] = st;
    }
    if (tid == 127) sstart[128] = tmp[127];
    __syncthreads();
    for (int i = tid; i < n; i += 256) {
        const unsigned int ent = reg[i];
        const int pos = atomicAdd(&scur[ent & 127u], 1);
        sorted[pos] = (ent >> 7) << 8;  // src row byte offset
    }
    __syncthreads();

    const unsigned int lane4 = lane * 4;
    unsigned int* tileW = (unsigned int*)tile;
#pragma unroll 1
    for (int k = 0; k < 32; ++k) {
        const int seg = wid * 32 + k;
        const int s0 = sstart[seg], s1 = sstart[seg + 1];
        float ax = 0.f, ay = 0.f;
        for (int base = s0; base < s1; base += 8) {
            unsigned int off[8];
#pragma unroll
            for (int j = 0; j < 8; ++j) {
                const int ii = base + j;
                off[j] = (ii < s1) ? sorted[ii] : ZBYTE;
            }
            unsigned int v[8];
#pragma unroll
            for (int j = 0; j < 8; ++j)
                v[j] = *(const unsigned int*)(xbb + (size_t)(off[j] + lane4));
#pragma unroll
            for (int j = 0; j < 8; ++j) {
                ax += bflo(v[j]);
                ay += bfhi(v[j]);
            }
        }
        // seg -> node_local = seg>>1, list = seg&1; conflict-free write
        tileW[(seg >> 1) * 132 + (seg & 1) * 64 + lane] = f2bf2(ax, ay);
    }
    __syncthreads();

    const int lm = lane & 15;
    const int lk = lane >> 4;
    f32x4 acc[8];
#pragma unroll
    for (int nf = 0; nf < 8; ++nf) acc[nf] = (f32x4)(0.f);

    const int rl0 = wid * 16;
    int rowg = node0 + rl0 + lm;
    if (rowg > NNODES) rowg = NNODES;  // clamp into zero row
    const unsigned short* __restrict__ xb = (const unsigned short*)xbb;

    for (int c = 0; c < 3; ++c) {
#pragma unroll
        for (int s = 0; s < 4; ++s) {
            short8v a;
            if (c == 0)
                a = *(const short8v*)(xb + (size_t)rowg * 128 + s * 32 + lk * 8);
            else
                a = *(const short8v*)(tile + (rl0 + lm) * 264 +
                                      (c - 1) * 128 + s * 32 + lk * 8);
            const short8v* __restrict__ bp =
                (const short8v*)wb + ((size_t)(c * 4 + s) * 8) * 64 + lane;
#pragma unroll
            for (int nf = 0; nf < 8; ++nf)
                acc[nf] = __builtin_amdgcn_mfma_f32_16x16x32_bf16(
                    a, bp[nf * 64], acc[nf], 0, 0, 0);
        }
    }

    const int rbase = node0 + rl0 + lk * 4;
#pragma unroll
    for (int nf = 0; nf < 8; ++nf) {
        const int col = nf * 16 + lm;
        const float bv = bias[col];
#pragma unroll
        for (int r = 0; r < 4; ++r) {
            const int row = rbase + r;
            if (row < NNODES)
                out[(size_t)row * 128 + col] = acc[nf][r] + bv;
        }
    }
}

extern "C" void kernel_launch(void* const* d_in, const int* in_sizes, int n_in,
                              void* d_out, int out_size, void* d_ws, size_t ws_size,
                              hipStream_t stream) {
    const float* x     = (const float*)d_in[0];
    const void*  pos_e = d_in[1];
    const void*  neg_e = d_in[2];
    const float* W     = (const float*)d_in[3];
    const float* bias  = (const float*)d_in[4];
    float*       out   = (float*)d_out;

    const size_t XB = ((size_t)NNODES + 1) * DD * 2;   // 25.6 MB + zero row
    const size_t WB = 12 * 8 * 64 * 8 * 2;             // 98304 B
    const size_t GB = 8192;                            // cursors (NBUK ints)
    const size_t RB = (size_t)NBUK * BCAP * 4;         // 5.6 MB regions

    char* ws = (char*)d_ws;
    int* flag = (int*)ws;
    size_t off = 256;
    unsigned int*   xb      = (unsigned int*)(ws + off);   off += XB;
    unsigned short* wb      = (unsigned short*)(ws + off); off += WB;
    int*            gcur    = (int*)(ws + off);            off += GB;
    unsigned int*   regions = (unsigned int*)(ws + off);   off += RB;
    (void)ws_size;

    init_kernel<<<8, 256, 0, stream>>>(gcur, (const unsigned int*)pos_e, flag);

    prep_kernel<<<BINB + 25 + 512, 256, 0, stream>>>(
        (const float4*)x, (uint2*)xb, W, wb, pos_e, neg_e, flag, gcur, regions);

    aggemm_kernel<<<NBUK, 256, 0, stream>>>(
        (const char*)xb, gcur, regions, wb, bias, out);
}

// Round 11
// 102.527 us; speedup vs baseline: 8.0835x; 1.1644x over previous
//
#include <hip/hip_runtime.h>

#define NNODES 100000
#define NEDGES 500000
#define DD 128
#define NBUK 1563      // 64-node combined buckets: ceil(100000/64)
#define BCAP 896       // mean 640, sigma 25 -> +10 sigma
#define BINB 123       // bin blocks (123 * 8192 >= 1M edges)
#define ZBYTE ((unsigned int)NNODES << 8)  // byte offset of zero row in xb

typedef __attribute__((ext_vector_type(8))) short short8v;
typedef __attribute__((ext_vector_type(4))) float f32x4;

__device__ __forceinline__ unsigned short f2bf(float f) {
    unsigned int u = __float_as_uint(f);
    return (unsigned short)((u + 0x7FFFu + ((u >> 16) & 1u)) >> 16);
}
__device__ __forceinline__ unsigned int f2bf2(float a, float b) {
    return (unsigned int)f2bf(a) | ((unsigned int)f2bf(b) << 16);
}
__device__ __forceinline__ float bflo(unsigned int v) {
    return __uint_as_float(v << 16);
}
__device__ __forceinline__ float bfhi(unsigned int v) {
    return __uint_as_float(v & 0xFFFF0000u);
}

// ---------------------------------------------------------------------------
// Init: blocks [0,7) zero the 1563 bucket cursors; block 7 detects int64 vs
// int32 edge storage (odd 32-bit words all zero => int64).
// ---------------------------------------------------------------------------
__global__ __launch_bounds__(256) void init_kernel(
        int* __restrict__ gcur, const unsigned int* __restrict__ e,
        int* __restrict__ flag) {
    if (blockIdx.x < 7) {
        const int i = blockIdx.x * 256 + threadIdx.x;
        if (i < NBUK) gcur[i] = 0;
        return;
    }
    __shared__ unsigned int s_acc;
    if (threadIdx.x == 0) s_acc = 0u;
    __syncthreads();
    unsigned int v = 0u;
    for (int i = threadIdx.x; i < 4096; i += 256)
        v |= e[2 * i + 1];
    for (int off = 32; off > 0; off >>= 1)
        v |= __shfl_down(v, off, 64);
    if ((threadIdx.x & 63) == 0) atomicOr(&s_acc, v);
    __syncthreads();
    if (threadIdx.x == 0) *flag = (s_acc == 0u) ? 1 : 0;
}

// ---------------------------------------------------------------------------
// Fused prep. Block roles:
//   [0,BINB):      edge binning, 8192 edges/block, both passes batched 8-deep.
//   [BINB,+24):    W (fp32 [384][128]) -> fragment-packed bf16 wb.
//   BINB+24:       zero row of xb at index NNODES (padding/clamp target).
//   [BINB+25,+512): x (fp32) -> xb (bf16 row-major).
// ---------------------------------------------------------------------------
__global__ __launch_bounds__(256) void prep_kernel(
        const float4* __restrict__ x4, uint2* __restrict__ xb2,
        const float* __restrict__ W, unsigned short* __restrict__ wb,
        const void* __restrict__ pe, const void* __restrict__ ne,
        const int* __restrict__ flag,
        int* __restrict__ gcur, unsigned int* __restrict__ regions) {
    const int b = blockIdx.x;
    if (b < BINB) {
        __shared__ int hist[NBUK];
        __shared__ int gbase[NBUK];
        const int tid = threadIdx.x;
        for (int i = tid; i < NBUK; i += 256) hist[i] = 0;
        __syncthreads();
        const int e0 = b * 8192;
        const int fl = *flag;
        // pass 1: LDS histogram of bucket ids, 8-deep batched loads
        for (int k0 = 0; k0 < 32; k0 += 8) {
            int dv[8];
            bool ok[8];
#pragma unroll
            for (int j = 0; j < 8; ++j) {
                const int i = e0 + (k0 + j) * 256 + tid;
                ok[j] = i < 2 * NEDGES;
                const int ic = ok[j] ? i : 0;
                const int list = ic >= NEDGES;
                const int e = ic - list * NEDGES;
                const void* ed = list ? ne : pe;
                dv[j] = fl ? (int)((const long long*)ed)[NEDGES + e]
                           : ((const int*)ed)[NEDGES + e];
            }
#pragma unroll
            for (int j = 0; j < 8; ++j)
                if (ok[j]) atomicAdd(&hist[dv[j] >> 6], 1);
        }
        __syncthreads();
        // reserve: one global atomic per (block,bucket)
        for (int i = tid; i < NBUK; i += 256) {
            const int h = hist[i];
            gbase[i] = h ? atomicAdd(&gcur[i], h) : 0;
            hist[i] = 0;  // reuse as local cursor
        }
        __syncthreads();
        // pass 2: place entries, 8-deep batched
        for (int k0 = 0; k0 < 32; k0 += 8) {
            unsigned int ent[8];
            int bk[8];
            bool ok[8];
#pragma unroll
            for (int j = 0; j < 8; ++j) {
                const int i = e0 + (k0 + j) * 256 + tid;
                ok[j] = i < 2 * NEDGES;
                const int ic = ok[j] ? i : 0;
                const int list = ic >= NEDGES;
                const int e = ic - list * NEDGES;
                int s, d;
                if (fl) {
                    const long long* p = (const long long*)(list ? ne : pe);
                    s = (int)p[e]; d = (int)p[NEDGES + e];
                } else {
                    const int* p = (const int*)(list ? ne : pe);
                    s = p[e]; d = p[NEDGES + e];
                }
                bk[j] = d >> 6;
                ent[j] = ((unsigned int)s << 7) |
                         ((unsigned int)(d & 63) << 1) | (unsigned int)list;
            }
            int pos[8];
#pragma unroll
            for (int j = 0; j < 8; ++j)
                if (ok[j]) pos[j] = gbase[bk[j]] + atomicAdd(&hist[bk[j]], 1);
#pragma unroll
            for (int j = 0; j < 8; ++j)
                if (ok[j] && pos[j] < BCAP)
                    regions[(size_t)bk[j] * BCAP + pos[j]] = ent[j];
        }
    } else if (b < BINB + 24) {
        // frag (s,nf) at ((s*8+nf)*64+lane)*8 shorts; lane l holds
        // B[k=32s+(l>>4)*8+j][n=16nf+(l&15)], j=0..7.
        const int t = (b - BINB) * 256 + threadIdx.x;
        const int l = t & 63;
        const int nf = (t >> 6) & 7;
        const int s = t >> 9;
        const int n = nf * 16 + (l & 15);
        const int k0 = s * 32 + (l >> 4) * 8;
        unsigned short* o = wb + (size_t)t * 8;
#pragma unroll
        for (int j = 0; j < 8; ++j)
            o[j] = f2bf(W[(size_t)(k0 + j) * DD + n]);
    } else if (b == BINB + 24) {
        if (threadIdx.x < 64)
            ((unsigned int*)xb2)[(size_t)NNODES * 64 + threadIdx.x] = 0u;
    } else {
        const int n = NNODES * DD / 4;
        for (int i = (b - BINB - 25) * 256 + threadIdx.x; i < n; i += 512 * 256) {
            const float4 v = x4[i];
            uint2 o;
            o.x = f2bf2(v.x, v.y);
            o.y = f2bf2(v.z, v.w);
            xb2[i] = o;
        }
    }
}

// ---------------------------------------------------------------------------
// Fused aggregate + GEMM: one block per 64-node bucket, 512 threads (8 waves)
// so the 39.9 KB LDS footprint still packs 4 blocks/CU but with 32 waves/CU
// (100% wave occupancy) to hide the random-row gather latency.
//   1) counting sort of entries by (node,list) segment (LDS int atomics)
//   2) gather: wave w owns segments [16w,16w+16); 8-deep batched row loads,
//      zero-row padding; bf16 agg -> LDS tile [64][264] (528B pitch)
//   3) MFMA: wave w = (row-group w&3) x (col-half w>>2): 16 rows x 64 cols,
//      A c=0 from global xb, c=1/2 from the tile; fp32 out + bias.
// ---------------------------------------------------------------------------
__global__ __launch_bounds__(512) void aggemm_kernel(
        const char* __restrict__ xbb,
        const int* __restrict__ gcur, const unsigned int* __restrict__ regions,
        const unsigned short* __restrict__ wb,
        const float* __restrict__ bias,
        float* __restrict__ out) {
    __shared__ unsigned short tile[64 * 264];  // 33.8 KB
    __shared__ unsigned int sorted[BCAP];
    __shared__ int cnt[128];
    __shared__ int tmp[128];
    __shared__ int sstart[129];
    __shared__ int scur[128];

    const int b = blockIdx.x;
    const int node0 = b * 64;
    const int tid = threadIdx.x;
    const int wid = tid >> 6;
    const int lane = tid & 63;

    int n = gcur[b];
    n = n < BCAP ? n : BCAP;
    const unsigned int* __restrict__ reg = regions + (size_t)b * BCAP;

    if (tid < 128) cnt[tid] = 0;
    __syncthreads();
    for (int i = tid; i < n; i += 512)
        atomicAdd(&cnt[reg[i] & 127u], 1);
    __syncthreads();
    if (tid < 128) tmp[tid] = cnt[tid];
    __syncthreads();
#pragma unroll
    for (int off = 1; off < 128; off <<= 1) {
        int v = 0;
        if (tid < 128 && tid >= off) v = tmp[tid - off];
        __syncthreads();
        if (tid < 128) tmp[tid] += v;
        __syncthreads();
    }
    if (tid < 128) {
        const int st = tmp[tid] - cnt[tid];
        sstart[tid] = st;
        scur[tid] = st;
    }
    if (tid == 127) sstart[128] = tmp[127];
    __syncthreads();
    for (int i = tid; i < n; i += 512) {
        const unsigned int ent = reg[i];
        const int pos = atomicAdd(&scur[ent & 127u], 1);
        sorted[pos] = (ent >> 7) << 8;  // src row byte offset
    }
    __syncthreads();

    const unsigned int lane4 = lane * 4;
    unsigned int* tileW = (unsigned int*)tile;
#pragma unroll 1
    for (int k = 0; k < 16; ++k) {
        const int seg = wid * 16 + k;
        const int s0 = sstart[seg], s1 = sstart[seg + 1];
        float ax = 0.f, ay = 0.f;
        for (int base = s0; base < s1; base += 8) {
            unsigned int off[8];
#pragma unroll
            for (int j = 0; j < 8; ++j) {
                const int ii = base + j;
                off[j] = (ii < s1) ? sorted[ii] : ZBYTE;
            }
            unsigned int v[8];
#pragma unroll
            for (int j = 0; j < 8; ++j)
                v[j] = *(const unsigned int*)(xbb + (size_t)(off[j] + lane4));
#pragma unroll
            for (int j = 0; j < 8; ++j) {
                ax += bflo(v[j]);
                ay += bfhi(v[j]);
            }
        }
        // seg -> node_local = seg>>1, list = seg&1; conflict-free write
        tileW[(seg >> 1) * 132 + (seg & 1) * 64 + lane] = f2bf2(ax, ay);
    }
    __syncthreads();

    const int lm = lane & 15;
    const int lk = lane >> 4;
    const int rg = wid & 3;        // row group (16 rows)
    const int ch = wid >> 2;       // col half (64 cols = 4 n-frags)
    const int rl0 = rg * 16;
    f32x4 acc[4];
#pragma unroll
    for (int nf = 0; nf < 4; ++nf) acc[nf] = (f32x4)(0.f);

    int rowg = node0 + rl0 + lm;
    if (rowg > NNODES) rowg = NNODES;  // clamp into zero row
    const unsigned short* __restrict__ xb = (const unsigned short*)xbb;

    for (int c = 0; c < 3; ++c) {
#pragma unroll
        for (int s = 0; s < 4; ++s) {
            short8v a;
            if (c == 0)
                a = *(const short8v*)(xb + (size_t)rowg * 128 + s * 32 + lk * 8);
            else
                a = *(const short8v*)(tile + (rl0 + lm) * 264 +
                                      (c - 1) * 128 + s * 32 + lk * 8);
            const short8v* __restrict__ bp =
                (const short8v*)wb + ((size_t)((c * 4 + s) * 8 + ch * 4)) * 64 + lane;
#pragma unroll
            for (int nf = 0; nf < 4; ++nf)
                acc[nf] = __builtin_amdgcn_mfma_f32_16x16x32_bf16(
                    a, bp[nf * 64], acc[nf], 0, 0, 0);
        }
    }

    const int rbase = node0 + rl0 + lk * 4;
#pragma unroll
    for (int nf = 0; nf < 4; ++nf) {
        const int col = (ch * 4 + nf) * 16 + lm;
        const float bv = bias[col];
#pragma unroll
        for (int r = 0; r < 4; ++r) {
            const int row = rbase + r;
            if (row < NNODES)
                out[(size_t)row * 128 + col] = acc[nf][r] + bv;
        }
    }
}

extern "C" void kernel_launch(void* const* d_in, const int* in_sizes, int n_in,
                              void* d_out, int out_size, void* d_ws, size_t ws_size,
                              hipStream_t stream) {
    const float* x     = (const float*)d_in[0];
    const void*  pos_e = d_in[1];
    const void*  neg_e = d_in[2];
    const float* W     = (const float*)d_in[3];
    const float* bias  = (const float*)d_in[4];
    float*       out   = (float*)d_out;

    const size_t XB = ((size_t)NNODES + 1) * DD * 2;   // 25.6 MB + zero row
    const size_t WB = 12 * 8 * 64 * 8 * 2;             // 98304 B
    const size_t GB = 8192;                            // cursors (NBUK ints)
    const size_t RB = (size_t)NBUK * BCAP * 4;         // 5.6 MB regions

    char* ws = (char*)d_ws;
    int* flag = (int*)ws;
    size_t off = 256;
    unsigned int*   xb      = (unsigned int*)(ws + off);   off += XB;
    unsigned short* wb      = (unsigned short*)(ws + off); off += WB;
    int*            gcur    = (int*)(ws + off);            off += GB;
    unsigned int*   regions = (unsigned int*)(ws + off);   off += RB;
    (void)ws_size;

    init_kernel<<<8, 256, 0, stream>>>(gcur, (const unsigned int*)pos_e, flag);

    prep_kernel<<<BINB + 25 + 512, 256, 0, stream>>>(
        (const float4*)x, (uint2*)xb, W, wb, pos_e, neg_e, flag, gcur, regions);

    aggemm_kernel<<<NBUK, 512, 0, stream>>>(
        (const char*)xb, gcur, regions, wb, bias, out);
}

// Round 12
// 100.134 us; speedup vs baseline: 8.2767x; 1.0239x over previous
//
#include <hip/hip_runtime.h>

#define NNODES 100000
#define NEDGES 500000
#define DD 128
#define NBUK 1563      // 64-node combined buckets: ceil(100000/64)
#define BCAP 896       // mean 640, sigma 25 -> +10 sigma
#define BINB 123       // bin blocks (123 * 8192 >= 1M edges)
#define ZBYTE ((unsigned int)NNODES << 8)  // byte offset of zero row in xb

typedef __attribute__((ext_vector_type(8))) short short8v;
typedef __attribute__((ext_vector_type(4))) float f32x4;

__device__ __forceinline__ unsigned short f2bf(float f) {
    unsigned int u = __float_as_uint(f);
    return (unsigned short)((u + 0x7FFFu + ((u >> 16) & 1u)) >> 16);
}
__device__ __forceinline__ unsigned int f2bf2(float a, float b) {
    return (unsigned int)f2bf(a) | ((unsigned int)f2bf(b) << 16);
}
__device__ __forceinline__ float bflo(unsigned int v) {
    return __uint_as_float(v << 16);
}
__device__ __forceinline__ float bfhi(unsigned int v) {
    return __uint_as_float(v & 0xFFFF0000u);
}

// ---------------------------------------------------------------------------
// Init: blocks [0,7) zero the 1563 bucket cursors; block 7 detects int64 vs
// int32 edge storage (odd 32-bit words all zero => int64).
// ---------------------------------------------------------------------------
__global__ __launch_bounds__(256) void init_kernel(
        int* __restrict__ gcur, const unsigned int* __restrict__ e,
        int* __restrict__ flag) {
    if (blockIdx.x < 7) {
        const int i = blockIdx.x * 256 + threadIdx.x;
        if (i < NBUK) gcur[i] = 0;
        return;
    }
    __shared__ unsigned int s_acc;
    if (threadIdx.x == 0) s_acc = 0u;
    __syncthreads();
    unsigned int v = 0u;
    for (int i = threadIdx.x; i < 4096; i += 256)
        v |= e[2 * i + 1];
    for (int off = 32; off > 0; off >>= 1)
        v |= __shfl_down(v, off, 64);
    if ((threadIdx.x & 63) == 0) atomicOr(&s_acc, v);
    __syncthreads();
    if (threadIdx.x == 0) *flag = (s_acc == 0u) ? 1 : 0;
}

// ---------------------------------------------------------------------------
// Fused prep. Block roles:
//   [0,BINB):      edge binning, 8192 edges/block, both passes batched 8-deep.
//   [BINB,+24):    W (fp32 [384][128]) -> fragment-packed bf16 wb.
//   BINB+24:       zero row of xb at index NNODES (padding/clamp target).
//   [BINB+25,+512): x (fp32) -> xb (bf16 row-major).
// ---------------------------------------------------------------------------
__global__ __launch_bounds__(256) void prep_kernel(
        const float4* __restrict__ x4, uint2* __restrict__ xb2,
        const float* __restrict__ W, unsigned short* __restrict__ wb,
        const void* __restrict__ pe, const void* __restrict__ ne,
        const int* __restrict__ flag,
        int* __restrict__ gcur, unsigned int* __restrict__ regions) {
    const int b = blockIdx.x;
    if (b < BINB) {
        __shared__ int hist[NBUK];
        __shared__ int gbase[NBUK];
        const int tid = threadIdx.x;
        for (int i = tid; i < NBUK; i += 256) hist[i] = 0;
        __syncthreads();
        const int e0 = b * 8192;
        const int fl = *flag;
        // pass 1: LDS histogram of bucket ids, 8-deep batched loads
        for (int k0 = 0; k0 < 32; k0 += 8) {
            int dv[8];
            bool ok[8];
#pragma unroll
            for (int j = 0; j < 8; ++j) {
                const int i = e0 + (k0 + j) * 256 + tid;
                ok[j] = i < 2 * NEDGES;
                const int ic = ok[j] ? i : 0;
                const int list = ic >= NEDGES;
                const int e = ic - list * NEDGES;
                const void* ed = list ? ne : pe;
                dv[j] = fl ? (int)((const long long*)ed)[NEDGES + e]
                           : ((const int*)ed)[NEDGES + e];
            }
#pragma unroll
            for (int j = 0; j < 8; ++j)
                if (ok[j]) atomicAdd(&hist[dv[j] >> 6], 1);
        }
        __syncthreads();
        // reserve: one global atomic per (block,bucket)
        for (int i = tid; i < NBUK; i += 256) {
            const int h = hist[i];
            gbase[i] = h ? atomicAdd(&gcur[i], h) : 0;
            hist[i] = 0;  // reuse as local cursor
        }
        __syncthreads();
        // pass 2: place entries, 8-deep batched
        for (int k0 = 0; k0 < 32; k0 += 8) {
            unsigned int ent[8];
            int bk[8];
            bool ok[8];
#pragma unroll
            for (int j = 0; j < 8; ++j) {
                const int i = e0 + (k0 + j) * 256 + tid;
                ok[j] = i < 2 * NEDGES;
                const int ic = ok[j] ? i : 0;
                const int list = ic >= NEDGES;
                const int e = ic - list * NEDGES;
                int s, d;
                if (fl) {
                    const long long* p = (const long long*)(list ? ne : pe);
                    s = (int)p[e]; d = (int)p[NEDGES + e];
                } else {
                    const int* p = (const int*)(list ? ne : pe);
                    s = p[e]; d = p[NEDGES + e];
                }
                bk[j] = d >> 6;
                ent[j] = ((unsigned int)s << 7) |
                         ((unsigned int)(d & 63) << 1) | (unsigned int)list;
            }
            int pos[8];
#pragma unroll
            for (int j = 0; j < 8; ++j)
                if (ok[j]) pos[j] = gbase[bk[j]] + atomicAdd(&hist[bk[j]], 1);
#pragma unroll
            for (int j = 0; j < 8; ++j)
                if (ok[j] && pos[j] < BCAP)
                    regions[(size_t)bk[j] * BCAP + pos[j]] = ent[j];
        }
    } else if (b < BINB + 24) {
        // frag (s,nf) at ((s*8+nf)*64+lane)*8 shorts; lane l holds
        // B[k=32s+(l>>4)*8+j][n=16nf+(l&15)], j=0..7.
        const int t = (b - BINB) * 256 + threadIdx.x;
        const int l = t & 63;
        const int nf = (t >> 6) & 7;
        const int s = t >> 9;
        const int n = nf * 16 + (l & 15);
        const int k0 = s * 32 + (l >> 4) * 8;
        unsigned short* o = wb + (size_t)t * 8;
#pragma unroll
        for (int j = 0; j < 8; ++j)
            o[j] = f2bf(W[(size_t)(k0 + j) * DD + n]);
    } else if (b == BINB + 24) {
        if (threadIdx.x < 64)
            ((unsigned int*)xb2)[(size_t)NNODES * 64 + threadIdx.x] = 0u;
    } else {
        const int n = NNODES * DD / 4;
        for (int i = (b - BINB - 25) * 256 + threadIdx.x; i < n; i += 512 * 256) {
            const float4 v = x4[i];
            uint2 o;
            o.x = f2bf2(v.x, v.y);
            o.y = f2bf2(v.z, v.w);
            xb2[i] = o;
        }
    }
}

// ---------------------------------------------------------------------------
// Fused aggregate + GEMM: one block per 64-node bucket, 512 threads (8 waves).
//   1) counting sort of entries by (node,list) segment; sorted[] holds
//      (src*256 | seg) so the gather knows each row's target segment
//   2) FLAT gather: wave w streams its contiguous range
//      [sstart[16w], sstart[16w+16]) in 8-deep batches (pad only at range
//      end, ~10% overhead vs 72% for per-segment pad-to-8). Segment
//      transitions are wave-uniform; running (ax,ay) flushes into the bf16
//      tile via owner-exclusive LDS RMW. Tile rows pre-zeroed per wave.
//   3) MFMA: wave w = (row-group w&3) x (col-half w>>2); c=0 A-frags
//      PREFETCHED before the gather (T14: HBM latency hides under gather);
//      c=1/2 from the tile; fp32 out + bias.
// ---------------------------------------------------------------------------
__global__ __launch_bounds__(512) void aggemm_kernel(
        const char* __restrict__ xbb,
        const int* __restrict__ gcur, const unsigned int* __restrict__ regions,
        const unsigned short* __restrict__ wb,
        const float* __restrict__ bias,
        float* __restrict__ out) {
    __shared__ unsigned short tile[64 * 264];  // 33.8 KB, pitch 528B
    __shared__ unsigned int sorted[BCAP];
    __shared__ int cnt[128];
    __shared__ int tmp[128];
    __shared__ int sstart[129];
    __shared__ int scur[128];

    const int b = blockIdx.x;
    const int node0 = b * 64;
    const int tid = threadIdx.x;
    const int wid = tid >> 6;
    const int lane = tid & 63;

    int n = gcur[b];
    n = n < BCAP ? n : BCAP;
    const unsigned int* __restrict__ reg = regions + (size_t)b * BCAP;

    if (tid < 128) cnt[tid] = 0;
    __syncthreads();
    for (int i = tid; i < n; i += 512)
        atomicAdd(&cnt[reg[i] & 127u], 1);
    __syncthreads();
    if (tid < 128) tmp[tid] = cnt[tid];
    __syncthreads();
#pragma unroll
    for (int off = 1; off < 128; off <<= 1) {
        int v = 0;
        if (tid < 128 && tid >= off) v = tmp[tid - off];
        __syncthreads();
        if (tid < 128) tmp[tid] += v;
        __syncthreads();
    }
    if (tid < 128) {
        const int st = tmp[tid] - cnt[tid];
        sstart[tid] = st;
        scur[tid] = st;
    }
    if (tid == 127) sstart[128] = tmp[127];
    __syncthreads();
    for (int i = tid; i < n; i += 512) {
        const unsigned int ent = reg[i];
        const int pos = atomicAdd(&scur[ent & 127u], 1);
        sorted[pos] = ((ent >> 7) << 8) | (ent & 127u);  // src*256 | seg
    }
    __syncthreads();

    // --- T14 prefetch of c=0 A-frags (independent of gather) ---
    const int lm = lane & 15;
    const int lk = lane >> 4;
    const int rg = wid & 3;        // row group (16 rows)
    const int ch = wid >> 2;       // col half (64 cols = 4 n-frags)
    const int rl0 = rg * 16;
    int rowg = node0 + rl0 + lm;
    if (rowg > NNODES) rowg = NNODES;  // clamp into zero row
    const unsigned short* __restrict__ xb = (const unsigned short*)xbb;
    short8v a0pre[4];
#pragma unroll
    for (int s = 0; s < 4; ++s)
        a0pre[s] = *(const short8v*)(xb + (size_t)rowg * 128 + s * 32 + lk * 8);

    // --- flat gather ---
    unsigned int* tileW = (unsigned int*)tile;
#pragma unroll
    for (int r = 0; r < 8; ++r) {
        tileW[(wid * 8 + r) * 132 + lane] = 0u;
        tileW[(wid * 8 + r) * 132 + 64 + lane] = 0u;
    }
    const int lo = sstart[wid * 16];
    const int hi = sstart[wid * 16 + 16];
    const unsigned int lane4 = lane * 4;
    unsigned int cur = 255u;
    float ax = 0.f, ay = 0.f;
    for (int base = lo; base < hi; base += 8) {
        unsigned int ent[8];
#pragma unroll
        for (int j = 0; j < 8; ++j) {
            const int ii = base + j;
            ent[j] = (ii < hi) ? sorted[ii] : (ZBYTE | 255u);
        }
        unsigned int v[8];
#pragma unroll
        for (int j = 0; j < 8; ++j)
            v[j] = *(const unsigned int*)(
                xbb + (size_t)((ent[j] & 0xFFFFFF00u) + lane4));
#pragma unroll
        for (int j = 0; j < 8; ++j) {
            const unsigned int s = ent[j] & 255u;
            if (s != cur) {                      // wave-uniform branch
                if (cur != 255u) {
                    unsigned int* w =
                        &tileW[(cur >> 1) * 132 + (cur & 1) * 64 + lane];
                    const unsigned int o = *w;
                    *w = f2bf2(bflo(o) + ax, bfhi(o) + ay);
                }
                cur = s;
                ax = 0.f;
                ay = 0.f;
            }
            ax += bflo(v[j]);
            ay += bfhi(v[j]);
        }
    }
    if (cur != 255u) {
        unsigned int* w = &tileW[(cur >> 1) * 132 + (cur & 1) * 64 + lane];
        const unsigned int o = *w;
        *w = f2bf2(bflo(o) + ax, bfhi(o) + ay);
    }
    __syncthreads();

    // --- MFMA ---
    f32x4 acc[4];
#pragma unroll
    for (int nf = 0; nf < 4; ++nf) acc[nf] = (f32x4)(0.f);

    for (int c = 0; c < 3; ++c) {
#pragma unroll
        for (int s = 0; s < 4; ++s) {
            short8v a;
            if (c == 0)
                a = a0pre[s];
            else
                a = *(const short8v*)(tile + (rl0 + lm) * 264 +
                                      (c - 1) * 128 + s * 32 + lk * 8);
            const short8v* __restrict__ bp =
                (const short8v*)wb + ((size_t)((c * 4 + s) * 8 + ch * 4)) * 64 + lane;
#pragma unroll
            for (int nf = 0; nf < 4; ++nf)
                acc[nf] = __builtin_amdgcn_mfma_f32_16x16x32_bf16(
                    a, bp[nf * 64], acc[nf], 0, 0, 0);
        }
    }

    const int rbase = node0 + rl0 + lk * 4;
#pragma unroll
    for (int nf = 0; nf < 4; ++nf) {
        const int col = (ch * 4 + nf) * 16 + lm;
        const float bv = bias[col];
#pragma unroll
        for (int r = 0; r < 4; ++r) {
            const int row = rbase + r;
            if (row < NNODES)
                out[(size_t)row * 128 + col] = acc[nf][r] + bv;
        }
    }
}

extern "C" void kernel_launch(void* const* d_in, const int* in_sizes, int n_in,
                              void* d_out, int out_size, void* d_ws, size_t ws_size,
                              hipStream_t stream) {
    const float* x     = (const float*)d_in[0];
    const void*  pos_e = d_in[1];
    const void*  neg_e = d_in[2];
    const float* W     = (const float*)d_in[3];
    const float* bias  = (const float*)d_in[4];
    float*       out   = (float*)d_out;

    const size_t XB = ((size_t)NNODES + 1) * DD * 2;   // 25.6 MB + zero row
    const size_t WB = 12 * 8 * 64 * 8 * 2;             // 98304 B
    const size_t GB = 8192;                            // cursors (NBUK ints)
    const size_t RB = (size_t)NBUK * BCAP * 4;         // 5.6 MB regions

    char* ws = (char*)d_ws;
    int* flag = (int*)ws;
    size_t off = 256;
    unsigned int*   xb      = (unsigned int*)(ws + off);   off += XB;
    unsigned short* wb      = (unsigned short*)(ws + off); off += WB;
    int*            gcur    = (int*)(ws + off);            off += GB;
    unsigned int*   regions = (unsigned int*)(ws + off);   off += RB;
    (void)ws_size;

    init_kernel<<<8, 256, 0, stream>>>(gcur, (const unsigned int*)pos_e, flag);

    prep_kernel<<<BINB + 25 + 512, 256, 0, stream>>>(
        (const float4*)x, (uint2*)xb, W, wb, pos_e, neg_e, flag, gcur, regions);

    aggemm_kernel<<<NBUK, 512, 0, stream>>>(
        (const char*)xb, gcur, regions, wb, bias, out);
}